// Round 4
// baseline (313.672 us; speedup 1.0000x reference)
//
#include <hip/hip_runtime.h>
#include <hip/hip_bf16.h>
#include <math.h>

#define Bn 512
#define Vn 6890
#define Jn 24
#define NBn 10
#define Pn 207
#define N3n 20670   // Vn*3

// ---------------- Kernel 1: JS = Jreg@shapedirs, Jt = Jreg@v_template ----------------
// grid = 72 blocks (j*3+c), 256 threads
__global__ __launch_bounds__(256) void k_jsjt(
    const float* __restrict__ Jreg, const float* __restrict__ vtpl,
    const float* __restrict__ sdirs, float* __restrict__ JS, float* __restrict__ Jt)
{
  const int bid = blockIdx.x;           // 0..71 = j*3+c
  const int j = bid / 3, c = bid % 3;
  const int tid = threadIdx.x;
  float acc[11];
#pragma unroll
  for (int k = 0; k < 11; k++) acc[k] = 0.f;
  for (int v = tid; v < Vn; v += 256) {
    float w = Jreg[(size_t)j * Vn + v];
    int n = v * 3 + c;
#pragma unroll
    for (int l = 0; l < 10; l++) acc[l] += w * sdirs[(size_t)n * 10 + l];
    acc[10] += w * vtpl[n];
  }
  __shared__ float red[256];
  for (int k = 0; k < 11; k++) {
    red[tid] = acc[k];
    __syncthreads();
    for (int s = 128; s > 0; s >>= 1) {
      if (tid < s) red[tid] += red[tid + s];
      __syncthreads();
    }
    if (tid == 0) {
      if (k < 10) JS[bid * 10 + k] = red[0];
      else        Jt[bid] = red[0];
    }
    __syncthreads();
  }
}

// ---------------- Kernel 2: fully scalar per-batch pose pipeline ----------------
// 1 thread = 1 batch. grid = 8 blocks x 64 threads.
__global__ __launch_bounds__(64) void k_pose(
    const float* __restrict__ betas, const float* __restrict__ body_pose,
    const float* __restrict__ gorient, const float* __restrict__ transl,
    const float* __restrict__ JS, const float* __restrict__ Jt,
    float* __restrict__ pf_ws, float* __restrict__ Ar_ws,
    float* __restrict__ out_joints)
{
  const int b = blockIdx.x * 64 + threadIdx.x;
  if (b >= Bn) return;
  const int par[24] = {-1,0,0,0,1,2,3,4,5,6,7,8,9,9,9,12,13,14,16,17,18,19,20,21};

  float R[24][9];
  float jnt[24][3];
  float rel[24][3];
  float A[24][12];

  // rodrigues for all 24 joints
  for (int j = 0; j < 24; j++) {
    float x, y, z;
    if (j == 0) { x = gorient[b*3+0]; y = gorient[b*3+1]; z = gorient[b*3+2]; }
    else { int o = b*69 + (j-1)*3; x = body_pose[o]; y = body_pose[o+1]; z = body_pose[o+2]; }
    float ang = sqrtf(x*x + y*y + z*z) + 1e-8f;
    float inv = 1.0f / ang;
    float ux = x*inv, uy = y*inv, uz = z*inv;
    float s = sinf(ang), cc = cosf(ang), omc = 1.0f - cc;
    float K[9] = {0.f, -uz, uy,  uz, 0.f, -ux,  -uy, ux, 0.f};
#pragma unroll
    for (int mm = 0; mm < 3; mm++)
#pragma unroll
      for (int nn = 0; nn < 3; nn++) {
        float kk = K[mm*3+0]*K[0+nn] + K[mm*3+1]*K[3+nn] + K[mm*3+2]*K[6+nn];
        float eye = (mm == nn) ? 1.0f : 0.0f;
        R[j][mm*3+nn] = eye + s*K[mm*3+nn] + omc*kk;
      }
  }
  // unposed joints from betas (affine precompute)
  float bet[10];
#pragma unroll
  for (int l = 0; l < 10; l++) bet[l] = betas[b*10 + l];
  for (int idx = 0; idx < 72; idx++) {
    float a = Jt[idx];
#pragma unroll
    for (int l = 0; l < 10; l++) a += bet[l] * JS[idx*10 + l];
    jnt[idx/3][idx%3] = a;
  }
  // pose_feature = (R[1:] - I) flattened
  for (int j = 1; j < 24; j++)
    for (int e = 0; e < 9; e++) {
      float eye = (e == 0 || e == 4 || e == 8) ? 1.0f : 0.0f;
      pf_ws[(size_t)b * Pn + (j-1)*9 + e] = R[j][e] - eye;
    }
  // relative joints
  for (int c = 0; c < 3; c++) rel[0][c] = jnt[0][c];
  for (int j = 1; j < 24; j++)
    for (int c = 0; c < 3; c++) rel[j][c] = jnt[j][c] - jnt[par[j]][c];
  // kinematic chain: A_i = A_parent @ [[R_i, rel_i],[0,0,0,1]]
  for (int m = 0; m < 3; m++) {
    for (int nn = 0; nn < 3; nn++) A[0][m*4+nn] = R[0][m*3+nn];
    A[0][m*4+3] = rel[0][m];
  }
  for (int i = 1; i < 24; i++) {
    int p = par[i];
    for (int m = 0; m < 3; m++) {
      for (int nn = 0; nn < 3; nn++)
        A[i][m*4+nn] = A[p][m*4+0]*R[i][0+nn] + A[p][m*4+1]*R[i][3+nn] + A[p][m*4+2]*R[i][6+nn];
      A[i][m*4+3] = A[p][m*4+0]*rel[i][0] + A[p][m*4+1]*rel[i][1] + A[p][m*4+2]*rel[i][2] + A[p][m*4+3];
    }
  }
  // posed joints + transl -> output (second output region, fp32)
  for (int j = 0; j < 24; j++)
    for (int c = 0; c < 3; c++)
      out_joints[(size_t)b * 72 + j*3 + c] = A[j][c*4+3] + transl[b*3+c];
  // A_rel: [R | t - R*jnt]
  for (int j = 0; j < 24; j++)
    for (int m = 0; m < 3; m++) {
      float t = A[j][m*4+3] - (A[j][m*4+0]*jnt[j][0] + A[j][m*4+1]*jnt[j][1] + A[j][m*4+2]*jnt[j][2]);
      Ar_ws[(size_t)b * 288 + j*12 + m*4 + 0] = A[j][m*4+0];
      Ar_ws[(size_t)b * 288 + j*12 + m*4 + 1] = A[j][m*4+1];
      Ar_ws[(size_t)b * 288 + j*12 + m*4 + 2] = A[j][m*4+2];
      Ar_ws[(size_t)b * 288 + j*12 + m*4 + 3] = t;
    }
}

// ---------------- Kernel 3: fused v_shaped + pf@posedirs + skinning ----------------
// grid = (512/16, ceil(6890/128)), 192 threads. Each thread: 2 columns, 16 batches.
__global__ __launch_bounds__(192) void k_verts(
    const float* __restrict__ betas, const float* __restrict__ transl,
    const float* __restrict__ vtpl, const float* __restrict__ sdirs,
    const float* __restrict__ pdirs, const float* __restrict__ W,
    const float* __restrict__ pf_ws, const float* __restrict__ Ar_ws,
    float* __restrict__ out)
{
  const int tid = threadIdx.x;
  const int b0 = blockIdx.x * 16;
  const int v0 = blockIdx.y * 128;
  const int n0 = v0 * 3;

  __shared__ __align__(16) float pf_s[Pn][16];
  __shared__ __align__(16) float Ar_s[16][288];
  __shared__ __align__(16) float vp_s[16][384];
  __shared__ float betas_s[16][NBn];
  __shared__ float transl_s[16][3];

  for (int idx = tid; idx < Pn * 16; idx += 192) {
    int p = idx >> 4, bi = idx & 15;
    pf_s[p][bi] = pf_ws[(size_t)(b0 + bi) * Pn + p];
  }
  for (int idx = tid; idx < 16 * 288; idx += 192)
    Ar_s[idx / 288][idx % 288] = Ar_ws[(size_t)b0 * 288 + idx];
  for (int idx = tid; idx < 16 * NBn; idx += 192)
    betas_s[idx / NBn][idx % NBn] = betas[(size_t)b0 * NBn + idx];
  for (int idx = tid; idx < 48; idx += 192)
    transl_s[idx / 3][idx % 3] = transl[(size_t)b0 * 3 + idx];
  __syncthreads();

  const int n = n0 + 2 * tid;
  const bool valid = (n < N3n);   // n even, N3n even => n+1 also valid

  float acc0[16], acc1[16];
#pragma unroll
  for (int i = 0; i < 16; i++) { acc0[i] = 0.f; acc1[i] = 0.f; }

  for (int p = 0; p < Pn; p++) {
    float pd0 = 0.f, pd1 = 0.f;
    if (valid) {
      float2 t = *(const float2*)(pdirs + (size_t)p * N3n + n);
      pd0 = t.x; pd1 = t.y;
    }
    const float4* row = (const float4*)(pf_s[p]);   // wave-uniform -> broadcast
#pragma unroll
    for (int q = 0; q < 4; q++) {
      float4 f = row[q];
      acc0[4*q+0] += f.x * pd0;  acc1[4*q+0] += f.x * pd1;
      acc0[4*q+1] += f.y * pd0;  acc1[4*q+1] += f.y * pd1;
      acc0[4*q+2] += f.z * pd0;  acc1[4*q+2] += f.z * pd1;
      acc0[4*q+3] += f.w * pd0;  acc1[4*q+3] += f.w * pd1;
    }
  }

  // add v_shaped = v_template + betas . shapedirs
  float sd0[10], sd1[10];
  float vt0 = 0.f, vt1 = 0.f;
#pragma unroll
  for (int l = 0; l < 10; l++) { sd0[l] = 0.f; sd1[l] = 0.f; }
  if (valid) {
    const float4* s4 = (const float4*)(sdirs + (size_t)n * 10);
    float4 q0 = s4[0], q1 = s4[1], q2 = s4[2], q3 = s4[3], q4 = s4[4];
    sd0[0]=q0.x; sd0[1]=q0.y; sd0[2]=q0.z; sd0[3]=q0.w;
    sd0[4]=q1.x; sd0[5]=q1.y; sd0[6]=q1.z; sd0[7]=q1.w;
    sd0[8]=q2.x; sd0[9]=q2.y;
    sd1[0]=q2.z; sd1[1]=q2.w;
    sd1[2]=q3.x; sd1[3]=q3.y; sd1[4]=q3.z; sd1[5]=q3.w;
    sd1[6]=q4.x; sd1[7]=q4.y; sd1[8]=q4.z; sd1[9]=q4.w;
    float2 t = *(const float2*)(vtpl + n);
    vt0 = t.x; vt1 = t.y;
  }
#pragma unroll
  for (int bi = 0; bi < 16; bi++) {
    float s0 = vt0, s1 = vt1;
#pragma unroll
    for (int l = 0; l < 10; l++) {
      float bb = betas_s[bi][l];
      s0 += bb * sd0[l];
      s1 += bb * sd1[l];
    }
    acc0[bi] += s0;
    acc1[bi] += s1;
  }

  // stash v_posed (fp32)
#pragma unroll
  for (int bi = 0; bi < 16; bi++) {
    vp_s[bi][2*tid]   = acc0[bi];
    vp_s[bi][2*tid+1] = acc1[bi];
  }
  __syncthreads();

  // ---- skinning: wave-uniform m => LDS broadcasts
  const int m = tid / 64;        // output row 0..2
  const int vl = tid % 64;
  const int va = v0 + vl, vb = v0 + vl + 64;
  const bool va_ok = (va < Vn), vb_ok = (vb < Vn);

  float Wr0[24], Wr1[24];
#pragma unroll
  for (int j = 0; j < 24; j++) { Wr0[j] = 0.f; Wr1[j] = 0.f; }
  if (va_ok) {
    const float4* wp = (const float4*)(W + (size_t)va * 24);
#pragma unroll
    for (int q = 0; q < 6; q++) {
      float4 f = wp[q];
      Wr0[4*q] = f.x; Wr0[4*q+1] = f.y; Wr0[4*q+2] = f.z; Wr0[4*q+3] = f.w;
    }
  }
  if (vb_ok) {
    const float4* wp = (const float4*)(W + (size_t)vb * 24);
#pragma unroll
    for (int q = 0; q < 6; q++) {
      float4 f = wp[q];
      Wr1[4*q] = f.x; Wr1[4*q+1] = f.y; Wr1[4*q+2] = f.z; Wr1[4*q+3] = f.w;
    }
  }

  for (int bi = 0; bi < 16; bi++) {
    float Ta0=0.f,Ta1=0.f,Ta2=0.f,Ta3=0.f, Tb0=0.f,Tb1=0.f,Tb2=0.f,Tb3=0.f;
    const float4* arb = (const float4*)(Ar_s[bi]);
#pragma unroll
    for (int j = 0; j < 24; j++) {
      float4 a = arb[j*3 + m];   // wave-uniform address: broadcast
      float wa = Wr0[j], wb = Wr1[j];
      Ta0 += wa*a.x; Ta1 += wa*a.y; Ta2 += wa*a.z; Ta3 += wa*a.w;
      Tb0 += wb*a.x; Tb1 += wb*a.y; Tb2 += wb*a.z; Tb3 += wb*a.w;
    }
    float tr = transl_s[bi][m];
    if (va_ok) {
      float x = vp_s[bi][vl*3 + 0];
      float y = vp_s[bi][vl*3 + 1];
      float z = vp_s[bi][vl*3 + 2];
      out[((size_t)(b0+bi) * Vn + va) * 3 + m] = Ta0*x + Ta1*y + Ta2*z + Ta3 + tr;
    }
    if (vb_ok) {
      float x = vp_s[bi][(vl+64)*3 + 0];
      float y = vp_s[bi][(vl+64)*3 + 1];
      float z = vp_s[bi][(vl+64)*3 + 2];
      out[((size_t)(b0+bi) * Vn + vb) * 3 + m] = Tb0*x + Tb1*y + Tb2*z + Tb3 + tr;
    }
  }
}

extern "C" void kernel_launch(void* const* d_in, const int* in_sizes, int n_in,
                              void* d_out, int out_size, void* d_ws, size_t ws_size,
                              hipStream_t stream)
{
  // Route inputs by element count (robust to input-order permutations).
  const float *betas=nullptr, *bpose=nullptr, *gorient=nullptr, *transl=nullptr,
              *vtpl=nullptr, *sdirs=nullptr, *pdirs=nullptr, *Jreg=nullptr, *W=nullptr;
  int seen1536 = 0, seen165360 = 0;
  for (int i = 0; i < n_in; i++) {
    const float* p = (const float*)d_in[i];
    switch (in_sizes[i]) {
      case 5120:    betas = p; break;
      case 35328:   bpose = p; break;
      case 20670:   vtpl  = p; break;
      case 206700:  sdirs = p; break;
      case 4278690: pdirs = p; break;
      case 1536:    if (seen1536++ == 0) gorient = p; else transl = p; break;
      case 165360:  if (seen165360++ == 0) Jreg = p; else W = p; break;
      default: break;
    }
  }
  float* out = (float*)d_out;

  float* ws = (float*)d_ws;
  float* JS = ws;                       // 720
  float* Jt = ws + 720;                 // 72
  float* pf = ws + 792;                 // 512*207 = 105984
  float* Ar = ws + 792 + Bn * Pn;       // 512*288 = 147456

  k_jsjt<<<72, 256, 0, stream>>>(Jreg, vtpl, sdirs, JS, Jt);
  k_pose<<<Bn / 64, 64, 0, stream>>>(betas, bpose, gorient, transl, JS, Jt, pf, Ar,
                                     out + (size_t)Bn * Vn * 3);
  dim3 grid(Bn / 16, (Vn + 127) / 128);
  k_verts<<<grid, 192, 0, stream>>>(betas, transl, vtpl, sdirs, pdirs, W, pf, Ar, out);
}